// Round 1
// baseline (677.961 us; speedup 1.0000x reference)
//
#include <hip/hip_runtime.h>

// ---------------- problem constants ----------------
#define B_    2
#define S_    2048
#define HID_  3584
#define H_    16
#define KV_   8
#define D_    256
#define RQ_   6
#define NPROJ 2688
#define HD_   4096
#define MTOK  4096
#define EPS_  1e-6f
#define NEG_  -2.3819763e38f
#define SCALE_ 0.0625f   // 256^-0.5

typedef unsigned short u16;
typedef __attribute__((ext_vector_type(8))) short short8;
typedef __attribute__((ext_vector_type(4))) float f32x4;

__device__ __forceinline__ u16 f2bf(float f) {
  unsigned u = __float_as_uint(f);
  u += 0x7fffu + ((u >> 16) & 1u);
  return (u16)(u >> 16);
}

__device__ __forceinline__ void gl_lds16(const void* g, void* l) {
  __builtin_amdgcn_global_load_lds((__attribute__((address_space(1))) void*)g,
                                   (__attribute__((address_space(3))) void*)l, 16, 0, 0);
}

// ---------------- elementwise f32 -> bf16 ----------------
__global__ __launch_bounds__(256) void cvt_f32_bf16(const float* __restrict__ src,
                                                    u16* __restrict__ dst, int n) {
  int i = blockIdx.x * 256 + threadIdx.x;
  const int stride = gridDim.x * 256;
  const int n4 = n >> 2;
  for (; i < n4; i += stride) {
    float4 v = ((const float4*)src)[i];
    ushort4 o;
    o.x = f2bf(v.x); o.y = f2bf(v.y); o.z = f2bf(v.z); o.w = f2bf(v.w);
    ((ushort4*)dst)[i] = o;
  }
}

// ---------------- tiled transpose f32(RxC) -> bf16(CxR) ----------------
__global__ __launch_bounds__(256) void transpose_f32_bf16(const float* __restrict__ src,
                                                          u16* __restrict__ dst, int R, int C) {
  __shared__ float tile[32][33];
  const int tx = threadIdx.x & 31, ty = threadIdx.x >> 5;
  const int r0 = blockIdx.x << 5, c0 = blockIdx.y << 5;
#pragma unroll
  for (int j = 0; j < 4; ++j) {
    int r = r0 + ty + j * 8, c = c0 + tx;
    tile[ty + j * 8][tx] = (r < R && c < C) ? src[(size_t)r * C + c] : 0.f;
  }
  __syncthreads();
#pragma unroll
  for (int j = 0; j < 4; ++j) {
    int cc = c0 + ty + j * 8, rr = r0 + tx;
    if (cc < C && rr < R) dst[(size_t)cc * R + rr] = f2bf(tile[tx][ty + j * 8]);
  }
}

// ---------------- tiled transpose bf16(RxC)->bf16(CxR), batched z ----------------
__global__ __launch_bounds__(256) void transpose_bf16_b(const u16* __restrict__ src,
                                                        u16* __restrict__ dst, int R, int C) {
  __shared__ u16 tile[32][34];
  const size_t plane = (size_t)R * C;
  const u16* s = src + (size_t)blockIdx.z * plane;
  u16* d = dst + (size_t)blockIdx.z * plane;
  const int tx = threadIdx.x & 31, ty = threadIdx.x >> 5;
  const int r0 = blockIdx.x << 5, c0 = blockIdx.y << 5;
#pragma unroll
  for (int j = 0; j < 4; ++j) {
    int r = r0 + ty + j * 8, c = c0 + tx;
    tile[ty + j * 8][tx] = (r < R && c < C) ? s[(size_t)r * C + c] : (u16)0;
  }
  __syncthreads();
#pragma unroll
  for (int j = 0; j < 4; ++j) {
    int cc = c0 + ty + j * 8, rr = r0 + tx;
    if (cc < C && rr < R) d[(size_t)cc * R + rr] = tile[tx][ty + j * 8];
  }
}

// ---------------- m97-style 128x128 GEMM, A(MxK) row-major, Bm(NxK) row-major (B^T) ----
// C(MxN) f32.  BK=32, 4 waves, wave = 64x64 (4x4 frags of 16x16x32 bf16 MFMA).
__global__ __launch_bounds__(256, 2)
void gemm_bt(const u16* __restrict__ A, const u16* __restrict__ Bm, float* __restrict__ C,
             int M, int N, int K, int lda, int ldb, int ldc) {
  __shared__ __align__(16) u16 As[2][4096];
  __shared__ __align__(16) u16 Bs[2][4096];
  const int t = threadIdx.x;
  const int lane = t & 63;
  const int lq = lane & 15, lg = lane >> 4;
  const int wid = t >> 6;
  const int wr = wid >> 1, wc = wid & 1;
  const int m0 = blockIdx.x * 128, n0 = blockIdx.y * 128;

  // staging: per issue j (0,1): row = j*64 + t/4, 16B slot sl = t&3.
  // slot-XOR swizzle (involution): lds slot sl holds global slot sl ^ ((row>>1)&3)
  const int row0 = t >> 2;
  const int row1 = 64 + row0;
  const int sl = t & 3;
  const char* ga0 = (const char*)(A + (size_t)(m0 + row0) * lda) + ((sl ^ ((row0 >> 1) & 3)) << 4);
  const char* ga1 = (const char*)(A + (size_t)(m0 + row1) * lda) + ((sl ^ ((row1 >> 1) & 3)) << 4);
  const char* gb0 = (const char*)(Bm + (size_t)(n0 + row0) * ldb) + ((sl ^ ((row0 >> 1) & 3)) << 4);
  const char* gb1 = (const char*)(Bm + (size_t)(n0 + row1) * ldb) + ((sl ^ ((row1 >> 1) & 3)) << 4);
  u16* Abase = &As[0][0];
  u16* Bbase = &Bs[0][0];
  const int ldst0 = t * 8, ldst1 = 2048 + t * 8;

  int aoff[4], boff[4];
#pragma unroll
  for (int i = 0; i < 4; ++i) {
    int ra = wr * 64 + i * 16 + lq;
    aoff[i] = ra * 32 + ((lg ^ ((ra >> 1) & 3)) << 3);
    int rb = wc * 64 + i * 16 + lq;
    boff[i] = rb * 32 + ((lg ^ ((rb >> 1) & 3)) << 3);
  }

  f32x4 zero = {0.f, 0.f, 0.f, 0.f};
  f32x4 acc[4][4];
#pragma unroll
  for (int i = 0; i < 4; ++i)
#pragma unroll
    for (int j = 0; j < 4; ++j) acc[i][j] = zero;

  const int nk = K >> 5;
  gl_lds16(ga0, Abase + ldst0);
  gl_lds16(ga1, Abase + ldst1);
  gl_lds16(gb0, Bbase + ldst0);
  gl_lds16(gb1, Bbase + ldst1);
  __syncthreads();
  int cur = 0;
  for (int kt = 0; kt < nk; ++kt) {
    if (kt + 1 < nk) {
      const size_t ko = (size_t)(kt + 1) * 64;  // bytes: 32 bf16 per K-step
      const int nb = (cur ^ 1) * 4096;
      gl_lds16(ga0 + ko, Abase + nb + ldst0);
      gl_lds16(ga1 + ko, Abase + nb + ldst1);
      gl_lds16(gb0 + ko, Bbase + nb + ldst0);
      gl_lds16(gb1 + ko, Bbase + nb + ldst1);
    }
    const int cb = cur * 4096;
    short8 af[4], bfr[4];
#pragma unroll
    for (int i = 0; i < 4; ++i) {
      af[i] = *(const short8*)(Abase + cb + aoff[i]);
      bfr[i] = *(const short8*)(Bbase + cb + boff[i]);
    }
#pragma unroll
    for (int i = 0; i < 4; ++i)
#pragma unroll
      for (int j = 0; j < 4; ++j)
        acc[i][j] = __builtin_amdgcn_mfma_f32_16x16x32_bf16(af[i], bfr[j], acc[i][j], 0, 0, 0);
    __syncthreads();
    cur ^= 1;
  }
#pragma unroll
  for (int i = 0; i < 4; ++i)
#pragma unroll
    for (int j = 0; j < 4; ++j) {
      const int row = m0 + wr * 64 + i * 16 + lg * 4;
      const int col = n0 + wc * 64 + j * 16 + lq;
      float* cp = C + (size_t)row * ldc + col;
#pragma unroll
      for (int r = 0; r < 4; ++r) cp[(size_t)r * ldc] = acc[i][j][r];
    }
}

// ---------------- per-token RMSNorm + RoPE + rank contraction -> Q,K,V (bf16) ------
__global__ __launch_bounds__(256)
void build_qkv(const float* __restrict__ P, const float* __restrict__ freqs,
               const float* __restrict__ qw, const float* __restrict__ kw,
               u16* __restrict__ Qg, u16* __restrict__ Kg, u16* __restrict__ Vg) {
  const int token = blockIdx.x;
  const int b = token >> 11, s = token & 2047;
  const int d = threadIdx.x;
  const float* row = P + (size_t)token * NPROJ;
  __shared__ float aL[128];
  __shared__ float rQ[6][256];
  __shared__ float rK[2][256];
  __shared__ float red[4][8];

  if (d < 128) aL[d] = row[d];
  float bq[6], bk[2], bv[2];
#pragma unroll
  for (int r = 0; r < 6; ++r) bq[r] = row[128 + r * 256 + d];
#pragma unroll
  for (int r = 0; r < 2; ++r) bk[r] = row[1664 + r * 256 + d];
#pragma unroll
  for (int r = 0; r < 2; ++r) bv[r] = row[2176 + r * 256 + d];

  float sq[8];
#pragma unroll
  for (int r = 0; r < 6; ++r) sq[r] = bq[r] * bq[r];
  sq[6] = bk[0] * bk[0];
  sq[7] = bk[1] * bk[1];
#pragma unroll
  for (int j = 0; j < 8; ++j) {
    sq[j] += __shfl_xor(sq[j], 32, 64);
    sq[j] += __shfl_xor(sq[j], 16, 64);
    sq[j] += __shfl_xor(sq[j], 8, 64);
    sq[j] += __shfl_xor(sq[j], 4, 64);
    sq[j] += __shfl_xor(sq[j], 2, 64);
    sq[j] += __shfl_xor(sq[j], 1, 64);
  }
  const int lane = d & 63, wv = d >> 6;
  if (lane == 0) {
#pragma unroll
    for (int j = 0; j < 8; ++j) red[wv][j] = sq[j];
  }
  __syncthreads();
  float inv[8];
#pragma unroll
  for (int j = 0; j < 8; ++j) {
    float ss = red[0][j] + red[1][j] + red[2][j] + red[3][j];
    inv[j] = rsqrtf(ss * (1.0f / 256.0f) + EPS_);
  }
  const float gq = 1.f + qw[d], gk = 1.f + kw[d];
#pragma unroll
  for (int r = 0; r < 6; ++r) rQ[r][d] = bq[r] * inv[r] * gq;
#pragma unroll
  for (int r = 0; r < 2; ++r) rK[r][d] = bk[r] * inv[6 + r] * gk;
  __syncthreads();

  const int dh = d & 127;
  const float co = freqs[(s * 128 + dh) * 2 + 0];
  const float sn = freqs[(s * 128 + dh) * 2 + 1];
  float q_ro[6], k_ro[2];
  if (d < 128) {
#pragma unroll
    for (int r = 0; r < 6; ++r) q_ro[r] = rQ[r][d] * co - rQ[r][d + 128] * sn;
#pragma unroll
    for (int r = 0; r < 2; ++r) k_ro[r] = rK[r][d] * co - rK[r][d + 128] * sn;
  } else {
#pragma unroll
    for (int r = 0; r < 6; ++r) q_ro[r] = rQ[r][d] * co + rQ[r][d - 128] * sn;
#pragma unroll
    for (int r = 0; r < 2; ++r) k_ro[r] = rK[r][d] * co + rK[r][d - 128] * sn;
  }
  const float qs = SCALE_ * (1.0f / 6.0f);
#pragma unroll
  for (int h = 0; h < 16; ++h) {
    float a = 0.f;
#pragma unroll
    for (int r = 0; r < 6; ++r) a += aL[h * 6 + r] * q_ro[r];
    Qg[((size_t)(b * H_ + h) * S_ + s) * D_ + d] = f2bf(a * qs);
  }
#pragma unroll
  for (int kv = 0; kv < 8; ++kv) {
    float ak = aL[96 + kv * 2] * k_ro[0] + aL[96 + kv * 2 + 1] * k_ro[1];
    Kg[((size_t)(b * KV_ + kv) * S_ + s) * D_ + d] = f2bf(ak * 0.5f);
    float av = aL[112 + kv * 2] * bv[0] + aL[112 + kv * 2 + 1] * bv[1];
    Vg[((size_t)(b * KV_ + kv) * S_ + s) * D_ + d] = f2bf(av * 0.5f);
  }
}

// ---------------- flash attention: QB=64 (4 waves x 16 rows), KVB=32, D=256 -------
// Qg (B,H,S,D) bf16 (pre-scaled), Kg (B,KV,S,D), VTg (B,KV,D,S), Og (B*S, H*D)
__global__ __launch_bounds__(256, 2)
void attn_kernel(const u16* __restrict__ Qg, const u16* __restrict__ Kg,
                 const u16* __restrict__ VTg, u16* __restrict__ Og) {
  __shared__ __align__(16) u16 Kbuf[2][8192];  // 32 kv x 256 d, 512B rows, slot^ (r&7)
  __shared__ __align__(16) u16 Vbuf[8192];     // 256 d x 32 kv, 64B rows, slot^((d>>1)&3)
  __shared__ __align__(16) u16 Pbuf[4][512];   // per-wave 16q x 32kv

  const int t = threadIdx.x;
  const int lane = t & 63;
  const int lq = lane & 15, lg = lane >> 4;
  const int wid = t >> 6;
  const int qt = blockIdx.x, h = blockIdx.y, b = blockIdx.z;
  const int q0 = qt * 64;
  const int kvh = h >> 1;

  const u16* Kplane = Kg + (size_t)(b * KV_ + kvh) * S_ * D_;
  const u16* VTplane = VTg + (size_t)(b * KV_ + kvh) * D_ * S_;

  // Q fragments in registers (A-frag rows = lq)
  const int qrow = q0 + wid * 16 + lq;
  const u16* Qrow = Qg + ((size_t)(b * H_ + h) * S_ + qrow) * D_;
  short8 qf[8];
#pragma unroll
  for (int ks = 0; ks < 8; ++ks) qf[ks] = *(const short8*)(Qrow + ks * 32 + lg * 8);

  // staging source offsets (element units, add kv0 terms per tile)
  int ksrc[4], vsrc[4];
#pragma unroll
  for (int i = 0; i < 4; ++i) {
    const int kr = i * 8 + (t >> 5);
    const int ksl = t & 31;
    ksrc[i] = kr * D_ + ((ksl ^ (kr & 7)) << 3);
    const int vr = i * 64 + (t >> 2);
    const int vsl = t & 3;
    vsrc[i] = vr * S_ + ((vsl ^ ((vr >> 1) & 3)) << 3);
  }
  u16* Kbase = &Kbuf[0][0];

  f32x4 zero = {0.f, 0.f, 0.f, 0.f};
  f32x4 oacc[16];
#pragma unroll
  for (int db = 0; db < 16; ++db) oacc[db] = zero;
  float m_r[4], l_r[4];
#pragma unroll
  for (int r = 0; r < 4; ++r) { m_r[r] = NEG_; l_r[r] = 0.f; }

  const int qro = q0 + wid * 16 + lg * 4;   // C-layout q rows
  const int ntiles = (q0 + 64) >> 5;

#pragma unroll
  for (int i = 0; i < 4; ++i) gl_lds16(Kplane + ksrc[i], Kbase + (i * 256 + t) * 8);
  __syncthreads();
  int cur = 0;
  for (int it = 0; it < ntiles; ++it) {
    const int kv0 = it * 32;
    // stage V(it) (single buffer) + prefetch K(it+1)
#pragma unroll
    for (int i = 0; i < 4; ++i) gl_lds16(VTplane + kv0 + vsrc[i], &Vbuf[(i * 256 + t) * 8]);
    if (it + 1 < ntiles) {
      const int kn = (it + 1) * 32;
      const int nb = (cur ^ 1) * 8192;
#pragma unroll
      for (int i = 0; i < 4; ++i)
        gl_lds16(Kplane + (size_t)kn * D_ + ksrc[i], Kbase + nb + (i * 256 + t) * 8);
    }
    // QK^T
    const int cb = cur * 8192;
    f32x4 sacc[2];
    sacc[0] = zero; sacc[1] = zero;
#pragma unroll
    for (int kb = 0; kb < 2; ++kb) {
      const int r = kb * 16 + lq;  // kv row (B-frag col = lq)
#pragma unroll
      for (int ks = 0; ks < 8; ++ks) {
        const int g = ks * 4 + lg;
        short8 kf = *(const short8*)(Kbase + cb + r * 256 + ((g ^ (r & 7)) << 3));
        sacc[kb] = __builtin_amdgcn_mfma_f32_16x16x32_bf16(qf[ks], kf, sacc[kb], 0, 0, 0);
      }
    }
    // softcap + causal mask + online softmax
    float p[2][4], tmax[4];
    unsigned mbits = 0;
#pragma unroll
    for (int r = 0; r < 4; ++r) tmax[r] = NEG_;
#pragma unroll
    for (int kb = 0; kb < 2; ++kb) {
      const int kv = kv0 + kb * 16 + lq;
#pragma unroll
      for (int r = 0; r < 4; ++r) {
        float x = sacc[kb][r];
        const float e = __expf(-fabsf(x) * (2.0f / 50.0f));
        float th = (1.f - e) / (1.f + e);
        x = copysignf(50.0f * th, x);
        const bool msk = kv > (qro + r);
        if (msk) { x = NEG_; mbits |= 1u << (kb * 4 + r); }
        p[kb][r] = x;
        tmax[r] = fmaxf(tmax[r], x);
      }
    }
    float c_r[4];
#pragma unroll
    for (int r = 0; r < 4; ++r) {
      float v = tmax[r];
      v = fmaxf(v, __shfl_xor(v, 1, 16));
      v = fmaxf(v, __shfl_xor(v, 2, 16));
      v = fmaxf(v, __shfl_xor(v, 4, 16));
      v = fmaxf(v, __shfl_xor(v, 8, 16));
      const float mnew = fmaxf(m_r[r], v);
      c_r[r] = __expf(m_r[r] - mnew);
      m_r[r] = mnew;
      const float s0 = ((mbits >> (r)) & 1u) ? 0.f : __expf(p[0][r] - mnew);
      const float s1 = ((mbits >> (4 + r)) & 1u) ? 0.f : __expf(p[1][r] - mnew);
      p[0][r] = s0; p[1][r] = s1;
      float ps = s0 + s1;
      ps += __shfl_xor(ps, 1, 16);
      ps += __shfl_xor(ps, 2, 16);
      ps += __shfl_xor(ps, 4, 16);
      ps += __shfl_xor(ps, 8, 16);
      l_r[r] = l_r[r] * c_r[r] + ps;
    }
#pragma unroll
    for (int db = 0; db < 16; ++db) {
      oacc[db][0] *= c_r[0]; oacc[db][1] *= c_r[1];
      oacc[db][2] *= c_r[2]; oacc[db][3] *= c_r[3];
    }
    __syncthreads();  // V(it) + K(it+1) staged & visible
    // P -> LDS (bf16), then PV
#pragma unroll
    for (int kb = 0; kb < 2; ++kb)
#pragma unroll
      for (int r = 0; r < 4; ++r)
        Pbuf[wid][(lg * 4 + r) * 32 + kb * 16 + lq] = f2bf(p[kb][r]);
    short8 pf = *(const short8*)&Pbuf[wid][lq * 32 + lg * 8];
#pragma unroll
    for (int db = 0; db < 16; ++db) {
      const int d = db * 16 + lq;
      short8 vf = *(const short8*)&Vbuf[d * 32 + ((lg ^ ((d >> 1) & 3)) << 3)];
      oacc[db] = __builtin_amdgcn_mfma_f32_16x16x32_bf16(pf, vf, oacc[db], 0, 0, 0);
    }
    __syncthreads();  // Vbuf / Kbuf[cur] consumed
    cur ^= 1;
  }
  // epilogue: divide by l, write bf16
#pragma unroll
  for (int r = 0; r < 4; ++r) {
    const float inv = 1.0f / l_r[r];
    u16* orow = Og + (size_t)(b * S_ + qro + r) * HD_ + h * D_;
#pragma unroll
    for (int db = 0; db < 16; ++db) orow[db * 16 + lq] = f2bf(oacc[db][r] * inv);
  }
}

// ---------------- launcher ----------------
extern "C" void kernel_launch(void* const* d_in, const int* in_sizes, int n_in,
                              void* d_out, int out_size, void* d_ws, size_t ws_size,
                              hipStream_t stream) {
  const float* hs    = (const float*)d_in[0];
  const float* freqs = (const float*)d_in[1];
  const float* W_A_q = (const float*)d_in[8];
  const float* W_A_k = (const float*)d_in[9];
  const float* W_A_v = (const float*)d_in[10];
  const float* W_B_q = (const float*)d_in[11];
  const float* W_B_k = (const float*)d_in[12];
  const float* W_B_v = (const float*)d_in[13];
  const float* Wo    = (const float*)d_in[14];
  const float* qw    = (const float*)d_in[15];
  const float* kw    = (const float*)d_in[16];
  float* out = (float*)d_out;

  char* ws = (char*)d_ws;
  u16* hsb = (u16*)(ws);                    // 4096x3584 bf16        (29,360,128)
  u16* WT  = (u16*)(ws + 29360128);         // 2688x3584 bf16        (19,267,584)
  u16* WoT = (u16*)(ws + 48627712);         // 3584x4096 bf16        (29,360,128)
  u16* Qg  = (u16*)(ws + 77987840);         // (B,H,S,D) bf16        (33,554,432)
  u16* Kg  = (u16*)(ws + 111542272);        // (B,KV,S,D) bf16       (16,777,216)
  u16* Vg  = (u16*)(ws + 128319488);        // (B,KV,S,D) bf16       (16,777,216)
  u16* VTg = (u16*)(ws + 145096704);        // (B,KV,D,S) bf16       (16,777,216)
  u16* AOg = (u16*)(ws + 161873920);        // (B*S, H*D) bf16       (33,554,432)
  float* Pout = (float*)d_out;              // 4096x2688 f32 scratch inside d_out

  cvt_f32_bf16<<<1024, 256, 0, stream>>>(hs, hsb, MTOK * HID_);
  transpose_f32_bf16<<<dim3(112, 3),   256, 0, stream>>>(W_A_q, WT + (size_t)0 * HID_,    HID_, 96);
  transpose_f32_bf16<<<dim3(112, 1),   256, 0, stream>>>(W_A_k, WT + (size_t)96 * HID_,   HID_, 16);
  transpose_f32_bf16<<<dim3(112, 1),   256, 0, stream>>>(W_A_v, WT + (size_t)112 * HID_,  HID_, 16);
  transpose_f32_bf16<<<dim3(112, 48),  256, 0, stream>>>(W_B_q, WT + (size_t)128 * HID_,  HID_, 1536);
  transpose_f32_bf16<<<dim3(112, 16),  256, 0, stream>>>(W_B_k, WT + (size_t)1664 * HID_, HID_, 512);
  transpose_f32_bf16<<<dim3(112, 16),  256, 0, stream>>>(W_B_v, WT + (size_t)2176 * HID_, HID_, 512);
  transpose_f32_bf16<<<dim3(128, 112), 256, 0, stream>>>(Wo, WoT, HD_, HID_);

  gemm_bt<<<dim3(32, 21), 256, 0, stream>>>(hsb, WT, Pout, MTOK, NPROJ, HID_, HID_, HID_, NPROJ);
  build_qkv<<<4096, 256, 0, stream>>>(Pout, freqs, qw, kw, Qg, Kg, Vg);
  transpose_bf16_b<<<dim3(64, 8, 16), 256, 0, stream>>>(Vg, VTg, S_, D_);
  attn_kernel<<<dim3(32, H_, B_), 256, 0, stream>>>(Qg, Kg, VTg, AOg);
  gemm_bt<<<dim3(32, 28), 256, 0, stream>>>(AOg, WoT, out, MTOK, HID_, HD_, HD_, HD_, HID_);
}